// Round 3
// baseline (2926.296 us; speedup 1.0000x reference)
//
#include <hip/hip_runtime.h>
#include <hip/hip_bf16.h>

#define DF 128
#define BSH 7                 // 128 nodes per bucket
#define BNODES (1 << BSH)
#define SRCBITS 17            // n <= 131072
#define SRCMASK ((1u << SRCBITS) - 1u)
#define NBLK 128              // partition blocks (counting-sort chunks)

typedef __attribute__((ext_vector_type(8))) short short8;   // 8 bf16 (4 VGPRs)
typedef __attribute__((ext_vector_type(4))) float floatx4;  // MFMA accumulator

__device__ __forceinline__ unsigned short f2bf(float f) {
  unsigned u = __float_as_uint(f);
  u += 0x7fffu + ((u >> 16) & 1u);   // round-to-nearest-even
  return (unsigned short)(u >> 16);
}

// ---------------- atomic-free bucketed partition (counting sort) ----------------

// pass 1: per-chunk LDS histogram over buckets -> histg[b*NBLK + blk]
__global__ __launch_bounds__(256) void part_count(const int* __restrict__ dst,
                                                  int* __restrict__ histg,
                                                  int e, int nb, int chunk) {
  __shared__ int h[1024];
  int t = threadIdx.x, blk = blockIdx.x;
  for (int i = t; i < nb; i += 256) h[i] = 0;
  __syncthreads();
  int s = blk * chunk, en = min(e, s + chunk);
  for (int i = s + t; i < en; i += 256) atomicAdd(&h[dst[i] >> BSH], 1);
  __syncthreads();
  for (int b = t; b < nb; b += 256) histg[b * NBLK + blk] = h[b];
}

// per-bucket exclusive scan over the NBLK=128 chunk counts (one wave per bucket)
__global__ __launch_bounds__(256) void scan_within_bucket(int* __restrict__ histg,
                                                          int* __restrict__ tot, int nb) {
  int wave = threadIdx.x >> 6, lane = threadIdx.x & 63;
  int b = blockIdx.x * 4 + wave;
  if (b >= nb) return;
  uint2* p = (uint2*)(histg + b * NBLK);
  uint2 v = p[lane];
  int s = (int)(v.x + v.y);
  int S = s;
#pragma unroll
  for (int o = 1; o < 64; o <<= 1) {
    int u = __shfl_up(S, o);
    if (lane >= o) S += u;
  }
  int e0 = S - s;  // exclusive position of this chunk's first edge within bucket
  p[lane] = make_uint2((unsigned)e0, (unsigned)(e0 + (int)v.x));
  if (lane == 63) tot[b] = S;
}

// exclusive scan over bucket totals (nb <= 1024); bko[nb] = e
__global__ __launch_bounds__(1024) void scan_tot(const int* __restrict__ tot,
                                                 int* __restrict__ bko, int nb, int e) {
  __shared__ int wsum[16];
  int t = threadIdx.x;
  int v = (t < nb) ? tot[t] : 0;
  int lane = t & 63, wid = t >> 6;
  int s = v;
#pragma unroll
  for (int off = 1; off < 64; off <<= 1) {
    int u = __shfl_up(s, off);
    if (lane >= off) s += u;
  }
  if (lane == 63) wsum[wid] = s;
  __syncthreads();
  if (wid == 0) {
    int ws = (lane < 16) ? wsum[lane] : 0;
#pragma unroll
    for (int off = 1; off < 16; off <<= 1) {
      int u = __shfl_up(ws, off);
      if (lane >= off) ws += u;
    }
    if (lane < 16) wsum[lane] = ws;
  }
  __syncthreads();
  int incl = s + ((wid > 0) ? wsum[wid - 1] : 0);
  if (t < nb) bko[t] = incl - v;
  if (t == 0) bko[nb] = e;
}

// pass 2: scatter packed edges to bucket-major order; cursors are block-local LDS
__global__ __launch_bounds__(256) void part_scatter(const int* __restrict__ src,
                                                    const int* __restrict__ dst,
                                                    const int* __restrict__ histg,
                                                    const int* __restrict__ bko,
                                                    unsigned* __restrict__ ebuf,
                                                    int e, int nb, int chunk) {
  __shared__ int cur[1024];
  int t = threadIdx.x, blk = blockIdx.x;
  for (int b = t; b < nb; b += 256) cur[b] = bko[b] + histg[b * NBLK + blk];
  __syncthreads();
  int s = blk * chunk, en = min(e, s + chunk);
  for (int i = s + t; i < en; i += 256) {
    int d = dst[i];
    int p = atomicAdd(&cur[d >> BSH], 1);
    ebuf[p] = ((unsigned)(d & (BNODES - 1)) << SRCBITS) | (unsigned)src[i];
  }
}

// per-node degree (computed once, reused by both layers)
__global__ __launch_bounds__(256) void deg_kernel(const unsigned* __restrict__ ebuf,
                                                  const int* __restrict__ bko,
                                                  int* __restrict__ deg, int n) {
  __shared__ int h[BNODES];
  int t = threadIdx.x, b = blockIdx.x;
  if (t < BNODES) h[t] = 0;
  __syncthreads();
  int s = bko[b], en = bko[b + 1];
  for (int i = s + t; i < en; i += 256) atomicAdd(&h[ebuf[i] >> SRCBITS], 1);
  __syncthreads();
  int g = (b << BSH) + t;
  if (t < BNODES && g < n) deg[g] = h[t];
}

// ---------------- dtype prep ----------------

__global__ void conv_x(const float* __restrict__ x, unsigned short* __restrict__ xb, int n4) {
  int i = blockIdx.x * 256 + threadIdx.x;
  if (i < n4) {
    float4 v = ((const float4*)x)[i];
    union { unsigned short u[4]; uint2 d; } o;
    o.u[0] = f2bf(v.x); o.u[1] = f2bf(v.y); o.u[2] = f2bf(v.z); o.u[3] = f2bf(v.w);
    ((uint2*)xb)[i] = o.d;
  }
}

// swizzle W[128][128] fp32 into MFMA-B fragment order (bf16)
__global__ void reorder_w(const float* __restrict__ W, unsigned short* __restrict__ wf) {
  int t = blockIdx.x * 256 + threadIdx.x;  // [0, 16384)
  int j = t & 7, lane = (t >> 3) & 63, ktnt = t >> 9;
  int nt = ktnt & 7, kt = ktnt >> 3;
  int k = kt * 32 + (lane >> 4) * 8 + j;
  int ncol = nt * 16 + (lane & 15);
  wf[t] = f2bf(W[k * DF + ncol]);
}

// ---------------- push-style mean aggregation, one block per bucket ----------------
// 64 KB LDS fp32 accumulator: even/odd bf16 planes so ds_add_f32 is bank-conflict-free.
__global__ __launch_bounds__(256) void agg_push(const unsigned* __restrict__ feat,
                                                const unsigned* __restrict__ ebuf,
                                                const int* __restrict__ bko,
                                                const int* __restrict__ deg,
                                                unsigned* __restrict__ out, int n) {
  __shared__ float pe[BNODES * 64];
  __shared__ float po[BNODES * 64];
  int t = threadIdx.x, b = blockIdx.x;
  int wave = t >> 6, lane = t & 63;
  for (int i = t; i < BNODES * 64; i += 256) { pe[i] = 0.f; po[i] = 0.f; }
  __syncthreads();
  int s = bko[b], en = bko[b + 1];
  int i = s + wave;
  for (; i + 28 < en; i += 32) {   // 4 waves stride-4, unroll 8 -> 8 gathers in flight
    unsigned p[8], u[8];
#pragma unroll
    for (int k = 0; k < 8; ++k) p[k] = ebuf[i + k * 4];
#pragma unroll
    for (int k = 0; k < 8; ++k) u[k] = feat[(p[k] & SRCMASK) * 64 + lane];
#pragma unroll
    for (int k = 0; k < 8; ++k) {
      int nd = (int)(p[k] >> SRCBITS);
      atomicAdd(&pe[nd * 64 + lane], __uint_as_float(u[k] << 16));
      atomicAdd(&po[nd * 64 + lane], __uint_as_float(u[k] & 0xffff0000u));
    }
  }
  for (; i < en; i += 4) {
    unsigned p = ebuf[i];
    unsigned u = feat[(p & SRCMASK) * 64 + lane];
    int nd = (int)(p >> SRCBITS);
    atomicAdd(&pe[nd * 64 + lane], __uint_as_float(u << 16));
    atomicAdd(&po[nd * 64 + lane], __uint_as_float(u & 0xffff0000u));
  }
  __syncthreads();
  int base = b << BSH;
  for (int j = t; j < BNODES * 64; j += 256) {
    int node = j >> 6, c = j & 63;
    int g = base + node;
    if (g < n) {
      float sc = 1.0f / (float)max(deg[g], 1);
      unsigned lo = f2bf(pe[j] * sc);
      unsigned hi = f2bf(po[j] * sc);
      out[g * 64 + c] = lo | (hi << 16);
    }
  }
}

// ---------------- fused SAGE linear: out = Aagg@Wl + Aself@Wr + b (opt relu) ----------------
__global__ __launch_bounds__(256) void gemm_sage(const unsigned short* __restrict__ Aagg,
                                                 const unsigned short* __restrict__ Aself,
                                                 const unsigned short* __restrict__ WFl,
                                                 const unsigned short* __restrict__ WFr,
                                                 const float* __restrict__ bias,
                                                 void* __restrict__ outp, int n,
                                                 int relu_out_bf16) {
  int wave = threadIdx.x >> 6;
  int lane = threadIdx.x & 63;
  int l16 = lane & 15, quad = lane >> 4;
  int rbase = (blockIdx.x * 4 + wave) * 32;
  if (rbase >= n) return;

  floatx4 acc[2][8];
#pragma unroll
  for (int a = 0; a < 2; ++a)
#pragma unroll
    for (int b = 0; b < 8; ++b) acc[a][b] = (floatx4)0.0f;

  int r0 = min(rbase + l16, n - 1);
  int r1 = min(rbase + 16 + l16, n - 1);

#pragma unroll
  for (int s = 0; s < 2; ++s) {
    const unsigned short* A = s ? Aself : Aagg;
    const unsigned short* W = s ? WFr : WFl;
#pragma unroll
    for (int kt = 0; kt < 4; ++kt) {
      short8 a0 = *(const short8*)(A + r0 * DF + kt * 32 + quad * 8);
      short8 a1 = *(const short8*)(A + r1 * DF + kt * 32 + quad * 8);
#pragma unroll
      for (int nt = 0; nt < 8; ++nt) {
        short8 bf = *(const short8*)(W + (((kt * 8 + nt) * 64) + lane) * 8);
        acc[0][nt] = __builtin_amdgcn_mfma_f32_16x16x32_bf16(a0, bf, acc[0][nt], 0, 0, 0);
        acc[1][nt] = __builtin_amdgcn_mfma_f32_16x16x32_bf16(a1, bf, acc[1][nt], 0, 0, 0);
      }
    }
  }

  float bv[8];
#pragma unroll
  for (int nt = 0; nt < 8; ++nt) bv[nt] = bias[nt * 16 + l16];

  // C/D mapping: col = lane&15, row = quad*4 + reg   [verified m89/m91]
  if (relu_out_bf16) {
    unsigned short* O = (unsigned short*)outp;
#pragma unroll
    for (int rb = 0; rb < 2; ++rb)
#pragma unroll
      for (int i = 0; i < 4; ++i) {
        int row = rbase + rb * 16 + quad * 4 + i;
        if (row < n) {
#pragma unroll
          for (int nt = 0; nt < 8; ++nt) {
            float v = acc[rb][nt][i] + bv[nt];
            O[row * DF + nt * 16 + l16] = f2bf(fmaxf(v, 0.0f));
          }
        }
      }
  } else {
    float* O = (float*)outp;
#pragma unroll
    for (int rb = 0; rb < 2; ++rb)
#pragma unroll
      for (int i = 0; i < 4; ++i) {
        int row = rbase + rb * 16 + quad * 4 + i;
        if (row < n) {
#pragma unroll
          for (int nt = 0; nt < 8; ++nt)
            O[row * DF + nt * 16 + l16] = acc[rb][nt][i] + bv[nt];
        }
      }
  }
}

// ---------------- launch ----------------

extern "C" void kernel_launch(void* const* d_in, const int* in_sizes, int n_in,
                              void* d_out, int out_size, void* d_ws, size_t ws_size,
                              hipStream_t stream) {
  const float* x   = (const float*)d_in[0];
  const int*   ei  = (const int*)d_in[1];
  const float* Wl1 = (const float*)d_in[2];
  const float* bl1 = (const float*)d_in[3];
  const float* Wr1 = (const float*)d_in[4];
  const float* Wl2 = (const float*)d_in[5];
  const float* bl2 = (const float*)d_in[6];
  const float* Wr2 = (const float*)d_in[7];

  int n = in_sizes[0] / DF;
  int e = in_sizes[1] / 2;
  const int* srcv = ei;
  const int* dstv = ei + e;
  int nb = (n + BNODES - 1) >> BSH;        // 782 buckets
  int chunk = (e + NBLK - 1) / NBLK;       // 12500 edges per partition block

  char* ws = (char*)d_ws;
  size_t off = 0;
  auto alloc = [&](size_t bytes) {
    void* p = ws + off;
    off = (off + bytes + 255) & ~(size_t)255;
    return p;
  };
  int* histg = (int*)alloc((size_t)nb * NBLK * 4);
  int* tot   = (int*)alloc(4096);
  int* bko   = (int*)alloc((size_t)(nb + 1) * 4);
  int* deg   = (int*)alloc((size_t)n * 4);
  unsigned* ebuf = (unsigned*)alloc((size_t)e * 4);
  unsigned short* xb   = (unsigned short*)alloc((size_t)n * DF * 2);
  unsigned short* hb   = (unsigned short*)alloc((size_t)n * DF * 2);
  unsigned short* aggb = (unsigned short*)alloc((size_t)n * DF * 2);
  unsigned short* wf   = (unsigned short*)alloc(4 * DF * DF * 2);
  unsigned short* wfl1 = wf;
  unsigned short* wfr1 = wf + 16384;
  unsigned short* wfl2 = wf + 32768;
  unsigned short* wfr2 = wf + 49152;

  part_count<<<NBLK, 256, 0, stream>>>(dstv, histg, e, nb, chunk);
  scan_within_bucket<<<(nb + 3) / 4, 256, 0, stream>>>(histg, tot, nb);
  scan_tot<<<1, 1024, 0, stream>>>(tot, bko, nb, e);
  part_scatter<<<NBLK, 256, 0, stream>>>(srcv, dstv, histg, bko, ebuf, e, nb, chunk);
  deg_kernel<<<nb, 256, 0, stream>>>(ebuf, bko, deg, n);

  conv_x<<<((n * DF / 4) + 255) / 256, 256, 0, stream>>>(x, xb, n * DF / 4);
  reorder_w<<<64, 256, 0, stream>>>(Wl1, wfl1);
  reorder_w<<<64, 256, 0, stream>>>(Wr1, wfr1);
  reorder_w<<<64, 256, 0, stream>>>(Wl2, wfl2);
  reorder_w<<<64, 256, 0, stream>>>(Wr2, wfr2);

  agg_push<<<nb, 256, 0, stream>>>((const unsigned*)xb, ebuf, bko, deg,
                                   (unsigned*)aggb, n);
  gemm_sage<<<(n + 127) / 128, 256, 0, stream>>>(aggb, xb, wfl1, wfr1, bl1, hb, n, 1);
  agg_push<<<nb, 256, 0, stream>>>((const unsigned*)hb, ebuf, bko, deg,
                                   (unsigned*)aggb, n);
  gemm_sage<<<(n + 127) / 128, 256, 0, stream>>>(aggb, hb, wfl2, wfr2, bl2, d_out, n, 0);
}

// Round 4
// 390.245 us; speedup vs baseline: 7.4986x; 7.4986x over previous
//
#include <hip/hip_runtime.h>
#include <hip/hip_bf16.h>

#define DF 128
#define BSH 7                 // 128 nodes per bucket
#define BNODES (1 << BSH)
#define SRCBITS 17            // n <= 131072
#define SRCMASK ((1u << SRCBITS) - 1u)
#define NBLK 128              // partition blocks (counting-sort chunks)

typedef __attribute__((ext_vector_type(8))) short short8;   // 8 bf16 (4 VGPRs)
typedef __attribute__((ext_vector_type(4))) float floatx4;  // MFMA accumulator

__device__ __forceinline__ unsigned short f2bf(float f) {
  unsigned u = __float_as_uint(f);
  u += 0x7fffu + ((u >> 16) & 1u);   // round-to-nearest-even
  return (unsigned short)(u >> 16);
}
__device__ __forceinline__ float bflo(unsigned u) { return __uint_as_float(u << 16); }
__device__ __forceinline__ float bfhi(unsigned u) { return __uint_as_float(u & 0xffff0000u); }

// ---------------- atomic-free bucketed partition (counting sort) ----------------

__global__ __launch_bounds__(256) void part_count(const int* __restrict__ dst,
                                                  int* __restrict__ histg,
                                                  int e, int nb, int chunk) {
  __shared__ int h[1024];
  int t = threadIdx.x, blk = blockIdx.x;
  for (int i = t; i < nb; i += 256) h[i] = 0;
  __syncthreads();
  int s = blk * chunk, en = min(e, s + chunk);
  for (int i = s + t; i < en; i += 256) atomicAdd(&h[dst[i] >> BSH], 1);
  __syncthreads();
  for (int b = t; b < nb; b += 256) histg[b * NBLK + blk] = h[b];
}

// per-bucket exclusive scan over the NBLK=128 chunk counts (one wave per bucket)
__global__ __launch_bounds__(256) void scan_within_bucket(int* __restrict__ histg,
                                                          int* __restrict__ tot, int nb) {
  int wave = threadIdx.x >> 6, lane = threadIdx.x & 63;
  int b = blockIdx.x * 4 + wave;
  if (b >= nb) return;
  uint2* p = (uint2*)(histg + b * NBLK);
  uint2 v = p[lane];
  int s = (int)(v.x + v.y);
  int S = s;
#pragma unroll
  for (int o = 1; o < 64; o <<= 1) {
    int u = __shfl_up(S, o);
    if (lane >= o) S += u;
  }
  int e0 = S - s;
  p[lane] = make_uint2((unsigned)e0, (unsigned)(e0 + (int)v.x));
  if (lane == 63) tot[b] = S;
}

// exclusive scan over bucket totals (nb <= 1024); bko[nb] = e
__global__ __launch_bounds__(1024) void scan_tot(const int* __restrict__ tot,
                                                 int* __restrict__ bko, int nb, int e) {
  __shared__ int wsum[16];
  int t = threadIdx.x;
  int v = (t < nb) ? tot[t] : 0;
  int lane = t & 63, wid = t >> 6;
  int s = v;
#pragma unroll
  for (int off = 1; off < 64; off <<= 1) {
    int u = __shfl_up(s, off);
    if (lane >= off) s += u;
  }
  if (lane == 63) wsum[wid] = s;
  __syncthreads();
  if (wid == 0) {
    int ws = (lane < 16) ? wsum[lane] : 0;
#pragma unroll
    for (int off = 1; off < 16; off <<= 1) {
      int u = __shfl_up(ws, off);
      if (lane >= off) ws += u;
    }
    if (lane < 16) wsum[lane] = ws;
  }
  __syncthreads();
  int incl = s + ((wid > 0) ? wsum[wid - 1] : 0);
  if (t < nb) bko[t] = incl - v;
  if (t == 0) bko[nb] = e;
}

// pass 2: scatter packed edges to bucket-major order; cursors are block-local LDS
__global__ __launch_bounds__(256) void part_scatter(const int* __restrict__ src,
                                                    const int* __restrict__ dst,
                                                    const int* __restrict__ histg,
                                                    const int* __restrict__ bko,
                                                    unsigned* __restrict__ ebuf,
                                                    int e, int nb, int chunk) {
  __shared__ int cur[1024];
  int t = threadIdx.x, blk = blockIdx.x;
  for (int b = t; b < nb; b += 256) cur[b] = bko[b] + histg[b * NBLK + blk];
  __syncthreads();
  int s = blk * chunk, en = min(e, s + chunk);
  for (int i = s + t; i < en; i += 256) {
    int d = dst[i];
    int p = atomicAdd(&cur[d >> BSH], 1);
    ebuf[p] = ((unsigned)(d & (BNODES - 1)) << SRCBITS) | (unsigned)src[i];
  }
}

// one block per bucket: LDS histogram over 128 local nodes -> LDS scan ->
// write rs[] (inclusive CSR ends) and sort bucket's edges into csr[]
__global__ __launch_bounds__(256) void fill_fine(const unsigned* __restrict__ ebuf,
                                                 const int* __restrict__ bko,
                                                 int* __restrict__ rs,
                                                 int* __restrict__ csr, int n) {
  __shared__ int hist[BNODES];
  __shared__ int cur[BNODES];
  __shared__ int wtot[2];
  int b = blockIdx.x;
  int t = threadIdx.x;
  if (t < BNODES) hist[t] = 0;
  __syncthreads();
  int s = bko[b], e = bko[b + 1];
  for (int i = s + t; i < e; i += 256)
    atomicAdd(&hist[ebuf[i] >> SRCBITS], 1);
  __syncthreads();
  int v = 0, sc = 0;
  if (t < BNODES) {
    v = hist[t];
    int lane = t & 63;
    sc = v;
#pragma unroll
    for (int off = 1; off < 64; off <<= 1) {
      int u = __shfl_up(sc, off);
      if (lane >= off) sc += u;
    }
    if (lane == 63) wtot[t >> 6] = sc;
  }
  __syncthreads();
  if (t < BNODES) {
    int incl = sc + ((t >= 64) ? wtot[0] : 0);
    cur[t] = incl - v;                 // bucket-relative exclusive start
    int node = (b << BSH) + t;
    if (node < n) rs[node] = s + incl; // global inclusive end
  }
  __syncthreads();
  for (int i = s + t; i < e; i += 256) {
    unsigned p = ebuf[i];
    int r = atomicAdd(&cur[p >> SRCBITS], 1);
    csr[s + r] = (int)(p & SRCMASK);
  }
}

// ---------------- dtype prep ----------------

__global__ void conv_x(const float* __restrict__ x, unsigned short* __restrict__ xb, int n4) {
  int i = blockIdx.x * 256 + threadIdx.x;
  if (i < n4) {
    float4 v = ((const float4*)x)[i];
    union { unsigned short u[4]; uint2 d; } o;
    o.u[0] = f2bf(v.x); o.u[1] = f2bf(v.y); o.u[2] = f2bf(v.z); o.u[3] = f2bf(v.w);
    ((uint2*)xb)[i] = o.d;
  }
}

// swizzle 4x W[128][128] fp32 into MFMA-B fragment order (bf16), one launch
__global__ void reorder_w4(const float* __restrict__ W0, const float* __restrict__ W1,
                           const float* __restrict__ W2, const float* __restrict__ W3,
                           unsigned short* __restrict__ wf) {
  int m = blockIdx.x >> 6;
  const float* W = (m == 0) ? W0 : (m == 1) ? W1 : (m == 2) ? W2 : W3;
  int t = (blockIdx.x & 63) * 256 + threadIdx.x;  // [0, 16384)
  int j = t & 7, lane = (t >> 3) & 63, ktnt = t >> 9;
  int nt = ktnt & 7, kt = ktnt >> 3;
  int k = kt * 32 + (lane >> 4) * 8 + j;
  int ncol = nt * 16 + (lane & 15);
  wf[m * 16384 + t] = f2bf(W[k * DF + ncol]);
}

// ---------------- pull mean aggregation: half-wave (32 lanes) per node ----------------
// feat rows = 32 x uint2 (256 B). Index-batch unroll 8 -> 8 gathers in flight.
__global__ __launch_bounds__(256) void agg_pull(const uint2* __restrict__ feat,
                                                const int* __restrict__ rs,
                                                const int* __restrict__ csr,
                                                uint2* __restrict__ out, int n) {
  int node = (blockIdx.x * 256 + threadIdx.x) >> 5;
  int l = threadIdx.x & 31;
  if (node >= n) return;
  int s = (node > 0) ? rs[node - 1] : 0;
  int e = rs[node];
  float a0 = 0.f, a1 = 0.f, a2 = 0.f, a3 = 0.f;
  int i = s;
  for (; i + 7 < e; i += 8) {
    int idx[8];
#pragma unroll
    for (int k = 0; k < 8; ++k) idx[k] = csr[i + k];      // independent broadcasts
    uint2 u[8];
#pragma unroll
    for (int k = 0; k < 8; ++k) u[k] = feat[idx[k] * 32 + l];  // 8 gathers in flight
#pragma unroll
    for (int k = 0; k < 8; ++k) {
      a0 += bflo(u[k].x); a1 += bfhi(u[k].x);
      a2 += bflo(u[k].y); a3 += bfhi(u[k].y);
    }
  }
  for (; i < e; ++i) {
    uint2 u = feat[csr[i] * 32 + l];
    a0 += bflo(u.x); a1 += bfhi(u.x);
    a2 += bflo(u.y); a3 += bfhi(u.y);
  }
  float sc = 1.0f / (float)max(e - s, 1);
  uint2 o;
  o.x = (unsigned)f2bf(a0 * sc) | ((unsigned)f2bf(a1 * sc) << 16);
  o.y = (unsigned)f2bf(a2 * sc) | ((unsigned)f2bf(a3 * sc) << 16);
  out[node * 32 + l] = o;
}

// ---------------- fused SAGE linear: out = Aagg@Wl + Aself@Wr + b (opt relu) ----------------
__global__ __launch_bounds__(256) void gemm_sage(const unsigned short* __restrict__ Aagg,
                                                 const unsigned short* __restrict__ Aself,
                                                 const unsigned short* __restrict__ WFl,
                                                 const unsigned short* __restrict__ WFr,
                                                 const float* __restrict__ bias,
                                                 void* __restrict__ outp, int n,
                                                 int relu_out_bf16) {
  int wave = threadIdx.x >> 6;
  int lane = threadIdx.x & 63;
  int l16 = lane & 15, quad = lane >> 4;
  int rbase = (blockIdx.x * 4 + wave) * 32;
  if (rbase >= n) return;

  floatx4 acc[2][8];
#pragma unroll
  for (int a = 0; a < 2; ++a)
#pragma unroll
    for (int b = 0; b < 8; ++b) acc[a][b] = (floatx4)0.0f;

  int r0 = min(rbase + l16, n - 1);
  int r1 = min(rbase + 16 + l16, n - 1);

#pragma unroll
  for (int s = 0; s < 2; ++s) {
    const unsigned short* A = s ? Aself : Aagg;
    const unsigned short* W = s ? WFr : WFl;
#pragma unroll
    for (int kt = 0; kt < 4; ++kt) {
      short8 a0 = *(const short8*)(A + r0 * DF + kt * 32 + quad * 8);
      short8 a1 = *(const short8*)(A + r1 * DF + kt * 32 + quad * 8);
#pragma unroll
      for (int nt = 0; nt < 8; ++nt) {
        short8 bf = *(const short8*)(W + (((kt * 8 + nt) * 64) + lane) * 8);
        acc[0][nt] = __builtin_amdgcn_mfma_f32_16x16x32_bf16(a0, bf, acc[0][nt], 0, 0, 0);
        acc[1][nt] = __builtin_amdgcn_mfma_f32_16x16x32_bf16(a1, bf, acc[1][nt], 0, 0, 0);
      }
    }
  }

  float bv[8];
#pragma unroll
  for (int nt = 0; nt < 8; ++nt) bv[nt] = bias[nt * 16 + l16];

  // C/D mapping: col = lane&15, row = quad*4 + reg   [verified m89/m91]
  if (relu_out_bf16) {
    unsigned short* O = (unsigned short*)outp;
#pragma unroll
    for (int rb = 0; rb < 2; ++rb)
#pragma unroll
      for (int i = 0; i < 4; ++i) {
        int row = rbase + rb * 16 + quad * 4 + i;
        if (row < n) {
#pragma unroll
          for (int nt = 0; nt < 8; ++nt) {
            float v = acc[rb][nt][i] + bv[nt];
            O[row * DF + nt * 16 + l16] = f2bf(fmaxf(v, 0.0f));
          }
        }
      }
  } else {
    float* O = (float*)outp;
#pragma unroll
    for (int rb = 0; rb < 2; ++rb)
#pragma unroll
      for (int i = 0; i < 4; ++i) {
        int row = rbase + rb * 16 + quad * 4 + i;
        if (row < n) {
#pragma unroll
          for (int nt = 0; nt < 8; ++nt)
            O[row * DF + nt * 16 + l16] = acc[rb][nt][i] + bv[nt];
        }
      }
  }
}

// ---------------- launch ----------------

extern "C" void kernel_launch(void* const* d_in, const int* in_sizes, int n_in,
                              void* d_out, int out_size, void* d_ws, size_t ws_size,
                              hipStream_t stream) {
  const float* x   = (const float*)d_in[0];
  const int*   ei  = (const int*)d_in[1];
  const float* Wl1 = (const float*)d_in[2];
  const float* bl1 = (const float*)d_in[3];
  const float* Wr1 = (const float*)d_in[4];
  const float* Wl2 = (const float*)d_in[5];
  const float* bl2 = (const float*)d_in[6];
  const float* Wr2 = (const float*)d_in[7];

  int n = in_sizes[0] / DF;
  int e = in_sizes[1] / 2;
  const int* srcv = ei;
  const int* dstv = ei + e;
  int nb = (n + BNODES - 1) >> BSH;        // 782 buckets
  int chunk = (e + NBLK - 1) / NBLK;       // 12500 edges per partition block

  char* ws = (char*)d_ws;
  size_t off = 0;
  auto alloc = [&](size_t bytes) {
    void* p = ws + off;
    off = (off + bytes + 255) & ~(size_t)255;
    return p;
  };
  int* histg = (int*)alloc((size_t)nb * NBLK * 4);
  int* tot   = (int*)alloc(4096);
  int* bko   = (int*)alloc((size_t)(nb + 1) * 4);
  int* rs    = (int*)alloc((size_t)n * 4);
  unsigned* ebuf = (unsigned*)alloc((size_t)e * 4);
  int* csr   = (int*)alloc((size_t)e * 4);
  unsigned short* xb   = (unsigned short*)alloc((size_t)n * DF * 2);
  unsigned short* hb   = (unsigned short*)alloc((size_t)n * DF * 2);
  unsigned short* aggb = (unsigned short*)alloc((size_t)n * DF * 2);
  unsigned short* wf   = (unsigned short*)alloc(4 * DF * DF * 2);
  unsigned short* wfl1 = wf;
  unsigned short* wfr1 = wf + 16384;
  unsigned short* wfl2 = wf + 32768;
  unsigned short* wfr2 = wf + 49152;

  part_count<<<NBLK, 256, 0, stream>>>(dstv, histg, e, nb, chunk);
  scan_within_bucket<<<(nb + 3) / 4, 256, 0, stream>>>(histg, tot, nb);
  scan_tot<<<1, 1024, 0, stream>>>(tot, bko, nb, e);
  part_scatter<<<NBLK, 256, 0, stream>>>(srcv, dstv, histg, bko, ebuf, e, nb, chunk);
  fill_fine<<<nb, 256, 0, stream>>>(ebuf, bko, rs, csr, n);

  conv_x<<<((n * DF / 4) + 255) / 256, 256, 0, stream>>>(x, xb, n * DF / 4);
  reorder_w4<<<256, 256, 0, stream>>>(Wl1, Wr1, Wl2, Wr2, wf);

  agg_pull<<<(n * 32 + 255) / 256, 256, 0, stream>>>((const uint2*)xb, rs, csr,
                                                     (uint2*)aggb, n);
  gemm_sage<<<(n + 127) / 128, 256, 0, stream>>>(aggb, xb, wfl1, wfr1, bl1, hb, n, 1);
  agg_pull<<<(n * 32 + 255) / 256, 256, 0, stream>>>((const uint2*)hb, rs, csr,
                                                     (uint2*)aggb, n);
  gemm_sage<<<(n + 127) / 128, 256, 0, stream>>>(aggb, hb, wfl2, wfr2, bl2, d_out, n, 0);
}

// Round 5
// 369.118 us; speedup vs baseline: 7.9278x; 1.0572x over previous
//
#include <hip/hip_runtime.h>
#include <hip/hip_bf16.h>

#define DF 128
#define BSH 7                 // 128 nodes per bucket
#define BNODES (1 << BSH)
#define SRCBITS 17            // n <= 131072
#define SRCMASK ((1u << SRCBITS) - 1u)
#define NBLK 512              // partition blocks (counting-sort chunks): 2 blocks/CU

typedef __attribute__((ext_vector_type(8))) short short8;   // 8 bf16 (4 VGPRs)
typedef __attribute__((ext_vector_type(4))) float floatx4;  // MFMA accumulator

__device__ __forceinline__ unsigned short f2bf(float f) {
  unsigned u = __float_as_uint(f);
  u += 0x7fffu + ((u >> 16) & 1u);   // round-to-nearest-even
  return (unsigned short)(u >> 16);
}
__device__ __forceinline__ float bflo(unsigned u) { return __uint_as_float(u << 16); }
__device__ __forceinline__ float bfhi(unsigned u) { return __uint_as_float(u & 0xffff0000u); }

// ---------------- atomic-free bucketed partition (counting sort) ----------------
// histg layout: [chunk][bucket] (transposed vs R3) -> contiguous per-block rows

__global__ __launch_bounds__(256) void part_count(const int* __restrict__ dst,
                                                  int* __restrict__ histg,
                                                  int e, int nb, int chunk) {
  __shared__ int h[1024];
  int t = threadIdx.x, blk = blockIdx.x;
  for (int i = t; i < nb; i += 256) h[i] = 0;
  __syncthreads();
  int s = blk * chunk, en = min(e, s + chunk);
  for (int i = s + t; i < en; i += 256) atomicAdd(&h[dst[i] >> BSH], 1);
  __syncthreads();
  for (int b = t; b < nb; b += 256) histg[blk * nb + b] = h[b];
}

// per-bucket exclusive scan over NBLK=512 chunk counts: one wave per bucket,
// 8 counts per lane. Rewrites histg[c][b] to within-bucket exclusive offsets.
__global__ __launch_bounds__(256) void scan_within_bucket(int* __restrict__ histg,
                                                          int* __restrict__ tot, int nb) {
  int wave = threadIdx.x >> 6, lane = threadIdx.x & 63;
  int b = blockIdx.x * 4 + wave;
  if (b >= nb) return;
  int v[8];
  int s = 0;
#pragma unroll
  for (int j = 0; j < 8; ++j) {
    v[j] = histg[(lane * 8 + j) * nb + b];
    s += v[j];
  }
  int S = s;
#pragma unroll
  for (int o = 1; o < 64; o <<= 1) {
    int u = __shfl_up(S, o);
    if (lane >= o) S += u;
  }
  int base = S - s;  // exclusive base for this lane's first chunk
#pragma unroll
  for (int j = 0; j < 8; ++j) {
    int c = v[j];
    histg[(lane * 8 + j) * nb + b] = base;
    base += c;
  }
  if (lane == 63) tot[b] = S;
}

// exclusive scan over bucket totals (nb <= 1024); bko[nb] = e
__global__ __launch_bounds__(1024) void scan_tot(const int* __restrict__ tot,
                                                 int* __restrict__ bko, int nb, int e) {
  __shared__ int wsum[16];
  int t = threadIdx.x;
  int v = (t < nb) ? tot[t] : 0;
  int lane = t & 63, wid = t >> 6;
  int s = v;
#pragma unroll
  for (int off = 1; off < 64; off <<= 1) {
    int u = __shfl_up(s, off);
    if (lane >= off) s += u;
  }
  if (lane == 63) wsum[wid] = s;
  __syncthreads();
  if (wid == 0) {
    int ws = (lane < 16) ? wsum[lane] : 0;
#pragma unroll
    for (int off = 1; off < 16; off <<= 1) {
      int u = __shfl_up(ws, off);
      if (lane >= off) ws += u;
    }
    if (lane < 16) wsum[lane] = ws;
  }
  __syncthreads();
  int incl = s + ((wid > 0) ? wsum[wid - 1] : 0);
  if (t < nb) bko[t] = incl - v;
  if (t == 0) bko[nb] = e;
}

// pass 2: scatter packed edges to bucket-major order; cursors are block-local LDS
__global__ __launch_bounds__(256) void part_scatter(const int* __restrict__ src,
                                                    const int* __restrict__ dst,
                                                    const int* __restrict__ histg,
                                                    const int* __restrict__ bko,
                                                    unsigned* __restrict__ ebuf,
                                                    int e, int nb, int chunk) {
  __shared__ int cur[1024];
  int t = threadIdx.x, blk = blockIdx.x;
  for (int b = t; b < nb; b += 256) cur[b] = bko[b] + histg[blk * nb + b];
  __syncthreads();
  int s = blk * chunk, en = min(e, s + chunk);
  for (int i = s + t; i < en; i += 256) {
    int d = dst[i];
    int p = atomicAdd(&cur[d >> BSH], 1);
    ebuf[p] = ((unsigned)(d & (BNODES - 1)) << SRCBITS) | (unsigned)src[i];
  }
}

// one block per bucket: LDS histogram over 128 local nodes -> LDS scan ->
// write rs[] (inclusive CSR ends) and sort bucket's edges into csr[]
__global__ __launch_bounds__(256) void fill_fine(const unsigned* __restrict__ ebuf,
                                                 const int* __restrict__ bko,
                                                 int* __restrict__ rs,
                                                 int* __restrict__ csr, int n) {
  __shared__ int hist[BNODES];
  __shared__ int cur[BNODES];
  __shared__ int wtot[2];
  int b = blockIdx.x;
  int t = threadIdx.x;
  if (t < BNODES) hist[t] = 0;
  __syncthreads();
  int s = bko[b], e = bko[b + 1];
  for (int i = s + t; i < e; i += 256)
    atomicAdd(&hist[ebuf[i] >> SRCBITS], 1);
  __syncthreads();
  int v = 0, sc = 0;
  if (t < BNODES) {
    v = hist[t];
    int lane = t & 63;
    sc = v;
#pragma unroll
    for (int off = 1; off < 64; off <<= 1) {
      int u = __shfl_up(sc, off);
      if (lane >= off) sc += u;
    }
    if (lane == 63) wtot[t >> 6] = sc;
  }
  __syncthreads();
  if (t < BNODES) {
    int incl = sc + ((t >= 64) ? wtot[0] : 0);
    cur[t] = incl - v;                 // bucket-relative exclusive start
    int node = (b << BSH) + t;
    if (node < n) rs[node] = s + incl; // global inclusive end
  }
  __syncthreads();
  for (int i = s + t; i < e; i += 256) {
    unsigned p = ebuf[i];
    int r = atomicAdd(&cur[p >> SRCBITS], 1);
    csr[s + r] = (int)(p & SRCMASK);
  }
}

// ---------------- dtype prep ----------------

__global__ void conv_x(const float* __restrict__ x, unsigned short* __restrict__ xb, int n4) {
  int i = blockIdx.x * 256 + threadIdx.x;
  if (i < n4) {
    float4 v = ((const float4*)x)[i];
    union { unsigned short u[4]; uint2 d; } o;
    o.u[0] = f2bf(v.x); o.u[1] = f2bf(v.y); o.u[2] = f2bf(v.z); o.u[3] = f2bf(v.w);
    ((uint2*)xb)[i] = o.d;
  }
}

// swizzle 4x W[128][128] fp32 into MFMA-B fragment order (bf16), one launch
__global__ void reorder_w4(const float* __restrict__ W0, const float* __restrict__ W1,
                           const float* __restrict__ W2, const float* __restrict__ W3,
                           unsigned short* __restrict__ wf) {
  int m = blockIdx.x >> 6;
  const float* W = (m == 0) ? W0 : (m == 1) ? W1 : (m == 2) ? W2 : W3;
  int t = (blockIdx.x & 63) * 256 + threadIdx.x;  // [0, 16384)
  int j = t & 7, lane = (t >> 3) & 63, ktnt = t >> 9;
  int nt = ktnt & 7, kt = ktnt >> 3;
  int k = kt * 32 + (lane >> 4) * 8 + j;
  int ncol = nt * 16 + (lane & 15);
  wf[m * 16384 + t] = f2bf(W[k * DF + ncol]);
}

// ---------------- pull mean aggregation: 16 lanes x uint4 per node ----------------
// feat rows = 16 x uint4 (256 B, dwordx4). Index-batch unroll 8 -> 8 gathers in flight.
__global__ __launch_bounds__(256) void agg_pull(const uint4* __restrict__ feat,
                                                const int* __restrict__ rs,
                                                const int* __restrict__ csr,
                                                uint4* __restrict__ out, int n) {
  int node = (blockIdx.x * 256 + threadIdx.x) >> 4;
  int l = threadIdx.x & 15;
  if (node >= n) return;
  int s = (node > 0) ? rs[node - 1] : 0;
  int e = rs[node];
  float a0 = 0.f, a1 = 0.f, a2 = 0.f, a3 = 0.f;
  float a4 = 0.f, a5 = 0.f, a6 = 0.f, a7 = 0.f;
  int i = s;
  for (; i + 7 < e; i += 8) {
    int idx[8];
#pragma unroll
    for (int k = 0; k < 8; ++k) idx[k] = csr[i + k];       // independent
    uint4 u[8];
#pragma unroll
    for (int k = 0; k < 8; ++k) u[k] = feat[idx[k] * 16 + l];  // 8 dwordx4 in flight
#pragma unroll
    for (int k = 0; k < 8; ++k) {
      a0 += bflo(u[k].x); a1 += bfhi(u[k].x);
      a2 += bflo(u[k].y); a3 += bfhi(u[k].y);
      a4 += bflo(u[k].z); a5 += bfhi(u[k].z);
      a6 += bflo(u[k].w); a7 += bfhi(u[k].w);
    }
  }
  for (; i < e; ++i) {
    uint4 u = feat[csr[i] * 16 + l];
    a0 += bflo(u.x); a1 += bfhi(u.x);
    a2 += bflo(u.y); a3 += bfhi(u.y);
    a4 += bflo(u.z); a5 += bfhi(u.z);
    a6 += bflo(u.w); a7 += bfhi(u.w);
  }
  float sc = 1.0f / (float)max(e - s, 1);
  uint4 o;
  o.x = (unsigned)f2bf(a0 * sc) | ((unsigned)f2bf(a1 * sc) << 16);
  o.y = (unsigned)f2bf(a2 * sc) | ((unsigned)f2bf(a3 * sc) << 16);
  o.z = (unsigned)f2bf(a4 * sc) | ((unsigned)f2bf(a5 * sc) << 16);
  o.w = (unsigned)f2bf(a6 * sc) | ((unsigned)f2bf(a7 * sc) << 16);
  out[node * 16 + l] = o;
}

// ---------------- fused SAGE linear: out = Aagg@Wl + Aself@Wr + b (opt relu) ----------------
__global__ __launch_bounds__(256) void gemm_sage(const unsigned short* __restrict__ Aagg,
                                                 const unsigned short* __restrict__ Aself,
                                                 const unsigned short* __restrict__ WFl,
                                                 const unsigned short* __restrict__ WFr,
                                                 const float* __restrict__ bias,
                                                 void* __restrict__ outp, int n,
                                                 int relu_out_bf16) {
  int wave = threadIdx.x >> 6;
  int lane = threadIdx.x & 63;
  int l16 = lane & 15, quad = lane >> 4;
  int rbase = (blockIdx.x * 4 + wave) * 32;
  if (rbase >= n) return;

  floatx4 acc[2][8];
#pragma unroll
  for (int a = 0; a < 2; ++a)
#pragma unroll
    for (int b = 0; b < 8; ++b) acc[a][b] = (floatx4)0.0f;

  int r0 = min(rbase + l16, n - 1);
  int r1 = min(rbase + 16 + l16, n - 1);

#pragma unroll
  for (int s = 0; s < 2; ++s) {
    const unsigned short* A = s ? Aself : Aagg;
    const unsigned short* W = s ? WFr : WFl;
#pragma unroll
    for (int kt = 0; kt < 4; ++kt) {
      short8 a0 = *(const short8*)(A + r0 * DF + kt * 32 + quad * 8);
      short8 a1 = *(const short8*)(A + r1 * DF + kt * 32 + quad * 8);
#pragma unroll
      for (int nt = 0; nt < 8; ++nt) {
        short8 bf = *(const short8*)(W + (((kt * 8 + nt) * 64) + lane) * 8);
        acc[0][nt] = __builtin_amdgcn_mfma_f32_16x16x32_bf16(a0, bf, acc[0][nt], 0, 0, 0);
        acc[1][nt] = __builtin_amdgcn_mfma_f32_16x16x32_bf16(a1, bf, acc[1][nt], 0, 0, 0);
      }
    }
  }

  float bv[8];
#pragma unroll
  for (int nt = 0; nt < 8; ++nt) bv[nt] = bias[nt * 16 + l16];

  // C/D mapping: col = lane&15, row = quad*4 + reg   [verified m89/m91]
  if (relu_out_bf16) {
    unsigned short* O = (unsigned short*)outp;
#pragma unroll
    for (int rb = 0; rb < 2; ++rb)
#pragma unroll
      for (int i = 0; i < 4; ++i) {
        int row = rbase + rb * 16 + quad * 4 + i;
        if (row < n) {
#pragma unroll
          for (int nt = 0; nt < 8; ++nt) {
            float v = acc[rb][nt][i] + bv[nt];
            O[row * DF + nt * 16 + l16] = f2bf(fmaxf(v, 0.0f));
          }
        }
      }
  } else {
    float* O = (float*)outp;
#pragma unroll
    for (int rb = 0; rb < 2; ++rb)
#pragma unroll
      for (int i = 0; i < 4; ++i) {
        int row = rbase + rb * 16 + quad * 4 + i;
        if (row < n) {
#pragma unroll
          for (int nt = 0; nt < 8; ++nt)
            O[row * DF + nt * 16 + l16] = acc[rb][nt][i] + bv[nt];
        }
      }
  }
}

// ---------------- launch ----------------

extern "C" void kernel_launch(void* const* d_in, const int* in_sizes, int n_in,
                              void* d_out, int out_size, void* d_ws, size_t ws_size,
                              hipStream_t stream) {
  const float* x   = (const float*)d_in[0];
  const int*   ei  = (const int*)d_in[1];
  const float* Wl1 = (const float*)d_in[2];
  const float* bl1 = (const float*)d_in[3];
  const float* Wr1 = (const float*)d_in[4];
  const float* Wl2 = (const float*)d_in[5];
  const float* bl2 = (const float*)d_in[6];
  const float* Wr2 = (const float*)d_in[7];

  int n = in_sizes[0] / DF;
  int e = in_sizes[1] / 2;
  const int* srcv = ei;
  const int* dstv = ei + e;
  int nb = (n + BNODES - 1) >> BSH;        // 782 buckets
  int chunk = (e + NBLK - 1) / NBLK;       // 3125 edges per partition block

  char* ws = (char*)d_ws;
  size_t off = 0;
  auto alloc = [&](size_t bytes) {
    void* p = ws + off;
    off = (off + bytes + 255) & ~(size_t)255;
    return p;
  };
  int* histg = (int*)alloc((size_t)nb * NBLK * 4);
  int* tot   = (int*)alloc(4096);
  int* bko   = (int*)alloc((size_t)(nb + 1) * 4);
  int* rs    = (int*)alloc((size_t)n * 4);
  unsigned* ebuf = (unsigned*)alloc((size_t)e * 4);
  int* csr   = (int*)alloc((size_t)e * 4);
  unsigned short* xb   = (unsigned short*)alloc((size_t)n * DF * 2);
  unsigned short* hb   = (unsigned short*)alloc((size_t)n * DF * 2);
  unsigned short* aggb = (unsigned short*)alloc((size_t)n * DF * 2);
  unsigned short* wf   = (unsigned short*)alloc(4 * DF * DF * 2);
  unsigned short* wfl1 = wf;
  unsigned short* wfr1 = wf + 16384;
  unsigned short* wfl2 = wf + 32768;
  unsigned short* wfr2 = wf + 49152;

  part_count<<<NBLK, 256, 0, stream>>>(dstv, histg, e, nb, chunk);
  scan_within_bucket<<<(nb + 3) / 4, 256, 0, stream>>>(histg, tot, nb);
  scan_tot<<<1, 1024, 0, stream>>>(tot, bko, nb, e);
  part_scatter<<<NBLK, 256, 0, stream>>>(srcv, dstv, histg, bko, ebuf, e, nb, chunk);
  fill_fine<<<nb, 256, 0, stream>>>(ebuf, bko, rs, csr, n);

  conv_x<<<((n * DF / 4) + 255) / 256, 256, 0, stream>>>(x, xb, n * DF / 4);
  reorder_w4<<<256, 256, 0, stream>>>(Wl1, Wr1, Wl2, Wr2, wf);

  agg_pull<<<(n * 16 + 255) / 256, 256, 0, stream>>>((const uint4*)xb, rs, csr,
                                                     (uint4*)aggb, n);
  gemm_sage<<<(n + 127) / 128, 256, 0, stream>>>(aggb, xb, wfl1, wfr1, bl1, hb, n, 1);
  agg_pull<<<(n * 16 + 255) / 256, 256, 0, stream>>>((const uint4*)hb, rs, csr,
                                                     (uint4*)aggb, n);
  gemm_sage<<<(n + 127) / 128, 256, 0, stream>>>(aggb, hb, wfl2, wfr2, bl2, d_out, n, 0);
}

// Round 6
// 361.565 us; speedup vs baseline: 8.0934x; 1.0209x over previous
//
#include <hip/hip_runtime.h>
#include <hip/hip_bf16.h>

#define DF 128
#define BSH 7                 // 128 nodes per bucket
#define BNODES (1 << BSH)
#define SRCBITS 17            // n <= 131072
#define SRCMASK ((1u << SRCBITS) - 1u)
#define NBLK 512              // partition blocks (counting-sort chunks): 2 blocks/CU
#define SLABSH 13             // src slab = src>>13 -> 16 slabs of <=8192 rows (1.6 MB)
#define NKEYS (BNODES * 16)   // fill_fine counting-sort keys

typedef __attribute__((ext_vector_type(8))) short short8;   // 8 bf16 (4 VGPRs)
typedef __attribute__((ext_vector_type(4))) float floatx4;  // MFMA accumulator

__device__ __forceinline__ unsigned short f2bf(float f) {
  unsigned u = __float_as_uint(f);
  u += 0x7fffu + ((u >> 16) & 1u);   // round-to-nearest-even
  return (unsigned short)(u >> 16);
}
__device__ __forceinline__ float bflo(unsigned u) { return __uint_as_float(u << 16); }
__device__ __forceinline__ float bfhi(unsigned u) { return __uint_as_float(u & 0xffff0000u); }

// ---------------- fused: coarse histogram (blocks < NBLK) + x->bf16 (rest) ----------------

__global__ __launch_bounds__(256) void count_and_conv(const int* __restrict__ dst,
                                                      int* __restrict__ histg,
                                                      int e, int nb, int chunk,
                                                      const float* __restrict__ x,
                                                      unsigned short* __restrict__ xb, int n4) {
  int t = threadIdx.x;
  if (blockIdx.x < NBLK) {
    __shared__ int h[1024];
    int blk = blockIdx.x;
    for (int i = t; i < nb; i += 256) h[i] = 0;
    __syncthreads();
    int s = blk * chunk, en = min(e, s + chunk);
    for (int i = s + t; i < en; i += 256) atomicAdd(&h[dst[i] >> BSH], 1);
    __syncthreads();
    for (int b = t; b < nb; b += 256) histg[blk * nb + b] = h[b];
  } else {
    int i = (blockIdx.x - NBLK) * 256 + t;
    if (i < n4) {
      float4 v = ((const float4*)x)[i];
      union { unsigned short u[4]; uint2 d; } o;
      o.u[0] = f2bf(v.x); o.u[1] = f2bf(v.y); o.u[2] = f2bf(v.z); o.u[3] = f2bf(v.w);
      ((uint2*)xb)[i] = o.d;
    }
  }
}

// ---------------- fused: per-bucket chunk scan (blocks < sb) + weight reorder ----------------
// scan part: one wave per bucket, 8 chunk-counts per lane; rewrites histg[c][b]
// to within-bucket exclusive offsets. reorder part: W[128][128] fp32 -> MFMA-B bf16 frags.
__global__ __launch_bounds__(256) void scan_and_reorder(int* __restrict__ histg,
                                                        int* __restrict__ tot, int nb, int sb,
                                                        const float* __restrict__ W0,
                                                        const float* __restrict__ W1,
                                                        const float* __restrict__ W2,
                                                        const float* __restrict__ W3,
                                                        unsigned short* __restrict__ wf) {
  if ((int)blockIdx.x < sb) {
    int wave = threadIdx.x >> 6, lane = threadIdx.x & 63;
    int b = blockIdx.x * 4 + wave;
    if (b >= nb) return;
    int v[8];
    int s = 0;
#pragma unroll
    for (int j = 0; j < 8; ++j) {
      v[j] = histg[(lane * 8 + j) * nb + b];
      s += v[j];
    }
    int S = s;
#pragma unroll
    for (int o = 1; o < 64; o <<= 1) {
      int u = __shfl_up(S, o);
      if (lane >= o) S += u;
    }
    int base = S - s;
#pragma unroll
    for (int j = 0; j < 8; ++j) {
      int c = v[j];
      histg[(lane * 8 + j) * nb + b] = base;
      base += c;
    }
    if (lane == 63) tot[b] = S;
  } else {
    int bb = blockIdx.x - sb;           // [0, 256)
    int m = bb >> 6;
    const float* W = (m == 0) ? W0 : (m == 1) ? W1 : (m == 2) ? W2 : W3;
    int t = (bb & 63) * 256 + threadIdx.x;  // [0, 16384)
    int j = t & 7, lane = (t >> 3) & 63, ktnt = t >> 9;
    int nt = ktnt & 7, kt = ktnt >> 3;
    int k = kt * 32 + (lane >> 4) * 8 + j;
    int ncol = nt * 16 + (lane & 15);
    wf[m * 16384 + t] = f2bf(W[k * DF + ncol]);
  }
}

// exclusive scan over bucket totals (nb <= 1024); bko[nb] = e
__global__ __launch_bounds__(1024) void scan_tot(const int* __restrict__ tot,
                                                 int* __restrict__ bko, int nb, int e) {
  __shared__ int wsum[16];
  int t = threadIdx.x;
  int v = (t < nb) ? tot[t] : 0;
  int lane = t & 63, wid = t >> 6;
  int s = v;
#pragma unroll
  for (int off = 1; off < 64; off <<= 1) {
    int u = __shfl_up(s, off);
    if (lane >= off) s += u;
  }
  if (lane == 63) wsum[wid] = s;
  __syncthreads();
  if (wid == 0) {
    int ws = (lane < 16) ? wsum[lane] : 0;
#pragma unroll
    for (int off = 1; off < 16; off <<= 1) {
      int u = __shfl_up(ws, off);
      if (lane >= off) ws += u;
    }
    if (lane < 16) wsum[lane] = ws;
  }
  __syncthreads();
  int incl = s + ((wid > 0) ? wsum[wid - 1] : 0);
  if (t < nb) bko[t] = incl - v;
  if (t == 0) bko[nb] = e;
}

// pass 2: scatter packed edges to bucket-major order; cursors are block-local LDS
__global__ __launch_bounds__(256) void part_scatter(const int* __restrict__ src,
                                                    const int* __restrict__ dst,
                                                    const int* __restrict__ histg,
                                                    const int* __restrict__ bko,
                                                    unsigned* __restrict__ ebuf,
                                                    int e, int nb, int chunk) {
  __shared__ int cur[1024];
  int t = threadIdx.x, blk = blockIdx.x;
  for (int b = t; b < nb; b += 256) cur[b] = bko[b] + histg[blk * nb + b];
  __syncthreads();
  int s = blk * chunk, en = min(e, s + chunk);
  for (int i = s + t; i < en; i += 256) {
    int d = dst[i];
    int p = atomicAdd(&cur[d >> BSH], 1);
    ebuf[p] = ((unsigned)(d & (BNODES - 1)) << SRCBITS) | (unsigned)src[i];
  }
}

// one block per bucket: counting sort by key=(dstLocal<<4)|(src>>SLABSH) ->
// per-node CSR lists grouped by src slab (sweep locality for agg_pull's gathers).
__global__ __launch_bounds__(256) void fill_fine(const unsigned* __restrict__ ebuf,
                                                 const int* __restrict__ bko,
                                                 int* __restrict__ rs,
                                                 int* __restrict__ csr, int n) {
  __shared__ int hist[NKEYS];
  __shared__ int cur[NKEYS];
  __shared__ int wsum[4];
  int b = blockIdx.x;
  int t = threadIdx.x;
  for (int i = t; i < NKEYS; i += 256) hist[i] = 0;
  __syncthreads();
  int s = bko[b], e = bko[b + 1];
  for (int i = s + t; i < e; i += 256) {
    unsigned p = ebuf[i];
    int key = (int)((p >> SRCBITS) << 4) | (int)((p & SRCMASK) >> SLABSH);
    atomicAdd(&hist[key], 1);
  }
  __syncthreads();
  // exclusive scan over 2048 keys: 8 consecutive keys per thread + block scan
  int v[8], sum = 0;
#pragma unroll
  for (int j = 0; j < 8; ++j) { v[j] = hist[t * 8 + j]; sum += v[j]; }
  int lane = t & 63, wid = t >> 6;
  int S = sum;
#pragma unroll
  for (int o = 1; o < 64; o <<= 1) {
    int u = __shfl_up(S, o);
    if (lane >= o) S += u;
  }
  if (lane == 63) wsum[wid] = S;
  __syncthreads();
  if (wid == 0 && lane < 4) {
    int ws = wsum[lane];
#pragma unroll
    for (int o = 1; o < 4; o <<= 1) {
      int u = __shfl_up(ws, o);
      if (lane >= o) ws += u;
    }
    wsum[lane] = ws;
  }
  __syncthreads();
  int base = (S - sum) + ((wid > 0) ? wsum[wid - 1] : 0);
#pragma unroll
  for (int j = 0; j < 8; ++j) { cur[t * 8 + j] = base; base += v[j]; }
  __syncthreads();
  // per-node inclusive CSR ends (read BEFORE scatter mutates cur)
  if (t < BNODES) {
    int g = (b << BSH) + t;
    if (g < n) {
      int endoff = (t == BNODES - 1) ? (e - s) : cur[(t + 1) << 4];
      rs[g] = s + endoff;
    }
  }
  __syncthreads();
  for (int i = s + t; i < e; i += 256) {
    unsigned p = ebuf[i];
    int key = (int)((p >> SRCBITS) << 4) | (int)((p & SRCMASK) >> SLABSH);
    int r = atomicAdd(&cur[key], 1);
    csr[s + r] = (int)(p & SRCMASK);
  }
}

// ---------------- pull mean aggregation: 16 lanes x uint4 per node ----------------
// csr lists are src-slab-sorted -> device-wide sweep keeps hot window in L2.
__global__ __launch_bounds__(256) void agg_pull(const uint4* __restrict__ feat,
                                                const int* __restrict__ rs,
                                                const int* __restrict__ csr,
                                                uint4* __restrict__ out, int n) {
  int node = (blockIdx.x * 256 + threadIdx.x) >> 4;
  int l = threadIdx.x & 15;
  if (node >= n) return;
  int s = (node > 0) ? rs[node - 1] : 0;
  int e = rs[node];
  float a0 = 0.f, a1 = 0.f, a2 = 0.f, a3 = 0.f;
  float a4 = 0.f, a5 = 0.f, a6 = 0.f, a7 = 0.f;
  int i = s;
  for (; i + 7 < e; i += 8) {
    int idx[8];
#pragma unroll
    for (int k = 0; k < 8; ++k) idx[k] = csr[i + k];       // independent
    uint4 u[8];
#pragma unroll
    for (int k = 0; k < 8; ++k) u[k] = feat[idx[k] * 16 + l];  // 8 dwordx4 in flight
#pragma unroll
    for (int k = 0; k < 8; ++k) {
      a0 += bflo(u[k].x); a1 += bfhi(u[k].x);
      a2 += bflo(u[k].y); a3 += bfhi(u[k].y);
      a4 += bflo(u[k].z); a5 += bfhi(u[k].z);
      a6 += bflo(u[k].w); a7 += bfhi(u[k].w);
    }
  }
  for (; i < e; ++i) {
    uint4 u = feat[csr[i] * 16 + l];
    a0 += bflo(u.x); a1 += bfhi(u.x);
    a2 += bflo(u.y); a3 += bfhi(u.y);
    a4 += bflo(u.z); a5 += bfhi(u.z);
    a6 += bflo(u.w); a7 += bfhi(u.w);
  }
  float sc = 1.0f / (float)max(e - s, 1);
  uint4 o;
  o.x = (unsigned)f2bf(a0 * sc) | ((unsigned)f2bf(a1 * sc) << 16);
  o.y = (unsigned)f2bf(a2 * sc) | ((unsigned)f2bf(a3 * sc) << 16);
  o.z = (unsigned)f2bf(a4 * sc) | ((unsigned)f2bf(a5 * sc) << 16);
  o.w = (unsigned)f2bf(a6 * sc) | ((unsigned)f2bf(a7 * sc) << 16);
  out[node * 16 + l] = o;
}

// ---------------- fused SAGE linear: out = Aagg@Wl + Aself@Wr + b (opt relu) ----------------
__global__ __launch_bounds__(256) void gemm_sage(const unsigned short* __restrict__ Aagg,
                                                 const unsigned short* __restrict__ Aself,
                                                 const unsigned short* __restrict__ WFl,
                                                 const unsigned short* __restrict__ WFr,
                                                 const float* __restrict__ bias,
                                                 void* __restrict__ outp, int n,
                                                 int relu_out_bf16) {
  int wave = threadIdx.x >> 6;
  int lane = threadIdx.x & 63;
  int l16 = lane & 15, quad = lane >> 4;
  int rbase = (blockIdx.x * 4 + wave) * 32;
  if (rbase >= n) return;

  floatx4 acc[2][8];
#pragma unroll
  for (int a = 0; a < 2; ++a)
#pragma unroll
    for (int b = 0; b < 8; ++b) acc[a][b] = (floatx4)0.0f;

  int r0 = min(rbase + l16, n - 1);
  int r1 = min(rbase + 16 + l16, n - 1);

#pragma unroll
  for (int s = 0; s < 2; ++s) {
    const unsigned short* A = s ? Aself : Aagg;
    const unsigned short* W = s ? WFr : WFl;
#pragma unroll
    for (int kt = 0; kt < 4; ++kt) {
      short8 a0 = *(const short8*)(A + r0 * DF + kt * 32 + quad * 8);
      short8 a1 = *(const short8*)(A + r1 * DF + kt * 32 + quad * 8);
#pragma unroll
      for (int nt = 0; nt < 8; ++nt) {
        short8 bf = *(const short8*)(W + (((kt * 8 + nt) * 64) + lane) * 8);
        acc[0][nt] = __builtin_amdgcn_mfma_f32_16x16x32_bf16(a0, bf, acc[0][nt], 0, 0, 0);
        acc[1][nt] = __builtin_amdgcn_mfma_f32_16x16x32_bf16(a1, bf, acc[1][nt], 0, 0, 0);
      }
    }
  }

  float bv[8];
#pragma unroll
  for (int nt = 0; nt < 8; ++nt) bv[nt] = bias[nt * 16 + l16];

  // C/D mapping: col = lane&15, row = quad*4 + reg   [verified m89/m91]
  if (relu_out_bf16) {
    unsigned short* O = (unsigned short*)outp;
#pragma unroll
    for (int rb = 0; rb < 2; ++rb)
#pragma unroll
      for (int i = 0; i < 4; ++i) {
        int row = rbase + rb * 16 + quad * 4 + i;
        if (row < n) {
#pragma unroll
          for (int nt = 0; nt < 8; ++nt) {
            float v = acc[rb][nt][i] + bv[nt];
            O[row * DF + nt * 16 + l16] = f2bf(fmaxf(v, 0.0f));
          }
        }
      }
  } else {
    float* O = (float*)outp;
#pragma unroll
    for (int rb = 0; rb < 2; ++rb)
#pragma unroll
      for (int i = 0; i < 4; ++i) {
        int row = rbase + rb * 16 + quad * 4 + i;
        if (row < n) {
#pragma unroll
          for (int nt = 0; nt < 8; ++nt)
            O[row * DF + nt * 16 + l16] = acc[rb][nt][i] + bv[nt];
        }
      }
  }
}

// ---------------- launch ----------------

extern "C" void kernel_launch(void* const* d_in, const int* in_sizes, int n_in,
                              void* d_out, int out_size, void* d_ws, size_t ws_size,
                              hipStream_t stream) {
  const float* x   = (const float*)d_in[0];
  const int*   ei  = (const int*)d_in[1];
  const float* Wl1 = (const float*)d_in[2];
  const float* bl1 = (const float*)d_in[3];
  const float* Wr1 = (const float*)d_in[4];
  const float* Wl2 = (const float*)d_in[5];
  const float* bl2 = (const float*)d_in[6];
  const float* Wr2 = (const float*)d_in[7];

  int n = in_sizes[0] / DF;
  int e = in_sizes[1] / 2;
  const int* srcv = ei;
  const int* dstv = ei + e;
  int nb = (n + BNODES - 1) >> BSH;        // 782 buckets
  int chunk = (e + NBLK - 1) / NBLK;       // 3125 edges per partition block

  char* ws = (char*)d_ws;
  size_t off = 0;
  auto alloc = [&](size_t bytes) {
    void* p = ws + off;
    off = (off + bytes + 255) & ~(size_t)255;
    return p;
  };
  int* histg = (int*)alloc((size_t)nb * NBLK * 4);
  int* tot   = (int*)alloc(4096);
  int* bko   = (int*)alloc((size_t)(nb + 1) * 4);
  int* rs    = (int*)alloc((size_t)n * 4);
  unsigned* ebuf = (unsigned*)alloc((size_t)e * 4);
  int* csr   = (int*)alloc((size_t)e * 4);
  unsigned short* xb   = (unsigned short*)alloc((size_t)n * DF * 2);
  unsigned short* hb   = (unsigned short*)alloc((size_t)n * DF * 2);
  unsigned short* aggb = (unsigned short*)alloc((size_t)n * DF * 2);
  unsigned short* wf   = (unsigned short*)alloc(4 * DF * DF * 2);
  unsigned short* wfl1 = wf;
  unsigned short* wfr1 = wf + 16384;
  unsigned short* wfl2 = wf + 32768;
  unsigned short* wfr2 = wf + 49152;

  int n4 = n * DF / 4;
  int cb = (n4 + 255) / 256;
  count_and_conv<<<NBLK + cb, 256, 0, stream>>>(dstv, histg, e, nb, chunk, x, xb, n4);
  int sb = (nb + 3) / 4;
  scan_and_reorder<<<sb + 256, 256, 0, stream>>>(histg, tot, nb, sb,
                                                 Wl1, Wr1, Wl2, Wr2, wf);
  scan_tot<<<1, 1024, 0, stream>>>(tot, bko, nb, e);
  part_scatter<<<NBLK, 256, 0, stream>>>(srcv, dstv, histg, bko, ebuf, e, nb, chunk);
  fill_fine<<<nb, 256, 0, stream>>>(ebuf, bko, rs, csr, n);

  agg_pull<<<(n * 16 + 255) / 256, 256, 0, stream>>>((const uint4*)xb, rs, csr,
                                                     (uint4*)aggb, n);
  gemm_sage<<<(n + 127) / 128, 256, 0, stream>>>(aggb, xb, wfl1, wfr1, bl1, hb, n, 1);
  agg_pull<<<(n * 16 + 255) / 256, 256, 0, stream>>>((const uint4*)hb, rs, csr,
                                                     (uint4*)aggb, n);
  gemm_sage<<<(n + 127) / 128, 256, 0, stream>>>(aggb, hb, wfl2, wfr2, bl2, d_out, n, 0);
}